// Round 1
// baseline (112.230 us; speedup 1.0000x reference)
//
#include <hip/hip_runtime.h>
#include <stdint.h>

typedef unsigned short u16;
typedef __attribute__((ext_vector_type(8))) short bf16x8;
typedef __attribute__((ext_vector_type(4))) float f32x4;

#define N_ROWS 16384
#define M_COLS 16384
#define DIM    64
#define SLICES 8
#define JTILE  64
#define JSLICE (M_COLS / SLICES)   /* 2048 */
#define NTILES (JSLICE / JTILE)    /* 32   */
#define LOG2E  1.44269504088896340736f

/* ---- workspace layout (bytes) ----
   x0b  bf16[N][64]   @ 0          (2 MB)
   x1b  bf16[M][64]   @ 2 MB
   s0   f32[N]        @ 4 MB
   s1   f32[M]        @ 4 MB + 64K
   num  f32[SLICES][N]@ 4 MB + 128K (512 KB)
   den  f32[SLICES][N]@ +512 KB
   total ~5.25 MB                                        */
#define OFF_X0B 0ull
#define OFF_X1B (OFF_X0B + (size_t)N_ROWS * DIM * 2)
#define OFF_S0  (OFF_X1B + (size_t)M_COLS * DIM * 2)
#define OFF_S1  (OFF_S0 + (size_t)N_ROWS * 4)
#define OFF_NUM (OFF_S1 + (size_t)M_COLS * 4)
#define OFF_DEN (OFF_NUM + (size_t)SLICES * N_ROWS * 4)

// ---------------- precompute: fp32 -> bf16 (RNE) + row squared norms --------
__global__ __launch_bounds__(256) void prep_kernel(
    const float* __restrict__ x0, const float* __restrict__ x1,
    u16* __restrict__ x0b, u16* __restrict__ x1b,
    float* __restrict__ s0, float* __restrict__ s1) {
  int wave = (blockIdx.x * 256 + threadIdx.x) >> 6;   // one wave per row
  int lane = threadIdx.x & 63;
  const float* src; u16* dstb; float* dsts; int row;
  if (wave < N_ROWS) { row = wave;          src = x0; dstb = x0b; dsts = s0; }
  else               { row = wave - N_ROWS; src = x1; dstb = x1b; dsts = s1; }
  float v = src[(size_t)row * DIM + lane];
  float sq = v * v;
  #pragma unroll
  for (int o = 32; o; o >>= 1) sq += __shfl_xor(sq, o);
  if (lane == 0) dsts[row] = sq;
  uint32_t u = __float_as_uint(v);
  u += 0x7FFFu + ((u >> 16) & 1u);          // round-to-nearest-even bf16
  dstb[(size_t)row * DIM + lane] = (u16)(u >> 16);
}

// ---------------- main: flash-style dist+softmax, bf16 MFMA ------------------
// Block = 256 thr (4 waves). Wave w owns i-rows [blk*256 + w*64, +64), A-frags
// in registers. j processed in 64-wide tiles from an m-slice (blockIdx.y).
__global__ __launch_bounds__(256, 2) void dist_softmax_kernel(
    const u16* __restrict__ x0b, const u16* __restrict__ x1b,
    const float* __restrict__ s0, const float* __restrict__ s1,
    const float* __restrict__ y, const float* __restrict__ alpha,
    float* __restrict__ numOut, float* __restrict__ denOut) {
  __shared__ u16 ldsB[JTILE * DIM];              // 8 KB, XOR-swizzled rows

  const int tid  = threadIdx.x;
  const int lane = tid & 63;
  const int w    = tid >> 6;
  const int r16  = lane & 15;
  const int g    = lane >> 4;
  const int iBase = blockIdx.x * 256 + w * 64;
  const int jSliceBase = blockIdx.y * JSLICE;
  const float c = -alpha[0] * LOG2E;             // exp(-a*d) = exp2(c*d)

  // A fragments (x0 rows) live in registers for the whole kernel.
  // lane layout (16x16x32 bf16): A[l&15][(l>>4)*8 + e]
  bf16x8 a[4][2];
  #pragma unroll
  for (int m2 = 0; m2 < 4; ++m2)
    #pragma unroll
    for (int kk = 0; kk < 2; ++kk) {
      int row = iBase + m2 * 16 + r16;
      int ke  = kk * 32 + g * 8;
      a[m2][kk] = *reinterpret_cast<const bf16x8*>(x0b + (size_t)row * DIM + ke);
    }

  // s0 per accumulator slot: C/D row = (l>>4)*4 + r within 16-tile m2
  float s0v[4][4];
  #pragma unroll
  for (int m2 = 0; m2 < 4; ++m2)
    #pragma unroll
    for (int r = 0; r < 4; ++r)
      s0v[m2][r] = s0[iBase + m2 * 16 + g * 4 + r];

  float num[4][4], den[4][4];
  #pragma unroll
  for (int m2 = 0; m2 < 4; ++m2)
    #pragma unroll
    for (int r = 0; r < 4; ++r) { num[m2][r] = 0.f; den[m2][r] = 0.f; }

  for (int jt = 0; jt < NTILES; ++jt) {
    const int jBase = jSliceBase + jt * JTILE;

    // stage x1b tile -> LDS, 16B/lane, source pre-swizzled (slot ^= row&7)
    #pragma unroll
    for (int rd = 0; rd < 2; ++rd) {
      int ci = rd * 256 + tid;                    // 16B-chunk index, 0..511
      int r  = ci >> 3;
      int s  = ci & 7;
      const u16* src = x1b + (size_t)(jBase + r) * DIM + ((s ^ (r & 7)) << 3);
      __builtin_amdgcn_global_load_lds(
          (const __attribute__((address_space(1))) unsigned int*)src,
          (__attribute__((address_space(3))) unsigned int*)(ldsB + ci * 8),
          16, 0, 0);
    }
    __syncthreads();   // compiler drains vmcnt(0) before s_barrier

    f32x4 acc[4][4];
    #pragma unroll
    for (int m2 = 0; m2 < 4; ++m2)
      #pragma unroll
      for (int nt = 0; nt < 4; ++nt)
        acc[m2][nt] = (f32x4){0.f, 0.f, 0.f, 0.f};

    #pragma unroll
    for (int kk = 0; kk < 2; ++kk) {
      bf16x8 b[4];
      #pragma unroll
      for (int nt = 0; nt < 4; ++nt) {
        int n    = nt * 16 + r16;
        int slot = (kk * 4 + g) ^ (n & 7);        // undo staging swizzle
        b[nt] = *reinterpret_cast<const bf16x8*>(ldsB + n * DIM + slot * 8);
      }
      #pragma unroll
      for (int m2 = 0; m2 < 4; ++m2)
        #pragma unroll
        for (int nt = 0; nt < 4; ++nt)
          acc[m2][nt] = __builtin_amdgcn_mfma_f32_16x16x32_bf16(
              a[m2][kk], b[nt], acc[m2][nt], 0, 0, 0);
    }

    // epilogue: d2 = s0 + s1 - 2*dot; e = exp2(c*sqrt(d2)); accumulate
    #pragma unroll
    for (int nt = 0; nt < 4; ++nt) {
      int col = jBase + nt * 16 + r16;
      float yv  = y[col];
      float s1v = s1[col];
      #pragma unroll
      for (int m2 = 0; m2 < 4; ++m2)
        #pragma unroll
        for (int r = 0; r < 4; ++r) {
          float d2 = fmaxf(fmaf(-2.0f, acc[m2][nt][r], s0v[m2][r] + s1v), 0.f);
          float e  = __builtin_amdgcn_exp2f(c * __builtin_amdgcn_sqrtf(d2));
          den[m2][r] += e;
          num[m2][r] += e * yv;
        }
    }
    __syncthreads();   // protect LDS before next tile's staging
  }

  // reduce across the 16 lanes sharing each output row (xor bits 0..3)
  #pragma unroll
  for (int m2 = 0; m2 < 4; ++m2)
    #pragma unroll
    for (int r = 0; r < 4; ++r) {
      float nv = num[m2][r], dv = den[m2][r];
      #pragma unroll
      for (int o = 1; o < 16; o <<= 1) {
        nv += __shfl_xor(nv, o);
        dv += __shfl_xor(dv, o);
      }
      if (r16 == 0) {
        int row = iBase + m2 * 16 + g * 4 + r;
        numOut[(size_t)blockIdx.y * N_ROWS + row] = nv;
        denOut[(size_t)blockIdx.y * N_ROWS + row] = dv;
      }
    }
}

// ---------------- combine slices ---------------------------------------------
__global__ __launch_bounds__(256) void combine_kernel(
    const float* __restrict__ num, const float* __restrict__ den,
    float* __restrict__ out) {
  int i = blockIdx.x * 256 + threadIdx.x;
  float nv = 0.f, dv = 0.f;
  #pragma unroll
  for (int s = 0; s < SLICES; ++s) {
    nv += num[(size_t)s * N_ROWS + i];
    dv += den[(size_t)s * N_ROWS + i];
  }
  out[i] = nv / dv;
}

extern "C" void kernel_launch(void* const* d_in, const int* in_sizes, int n_in,
                              void* d_out, int out_size, void* d_ws, size_t ws_size,
                              hipStream_t stream) {
  const float* x0    = (const float*)d_in[0];
  const float* x1    = (const float*)d_in[1];
  const float* y     = (const float*)d_in[2];
  const float* alpha = (const float*)d_in[3];
  float* out = (float*)d_out;

  char* ws = (char*)d_ws;
  u16*   x0b = (u16*)(ws + OFF_X0B);
  u16*   x1b = (u16*)(ws + OFF_X1B);
  float* s0  = (float*)(ws + OFF_S0);
  float* s1  = (float*)(ws + OFF_S1);
  float* num = (float*)(ws + OFF_NUM);
  float* den = (float*)(ws + OFF_DEN);

  // 1) bf16 conversion + row norms: one wave per row, 2*16384 rows
  prep_kernel<<<dim3(2 * N_ROWS / 4), dim3(256), 0, stream>>>(x0, x1, x0b, x1b, s0, s1);

  // 2) main: 64 i-blocks x 8 m-slices = 512 workgroups
  dist_softmax_kernel<<<dim3(N_ROWS / 256, SLICES), dim3(256), 0, stream>>>(
      x0b, x1b, s0, s1, y, alpha, num, den);

  // 3) combine partial num/den
  combine_kernel<<<dim3(N_ROWS / 256), dim3(256), 0, stream>>>(num, den, out);
}

// Round 2
// 89.380 us; speedup vs baseline: 1.2557x; 1.2557x over previous
//
#include <hip/hip_runtime.h>
#include <stdint.h>

typedef unsigned short u16;
typedef __attribute__((ext_vector_type(8))) short bf16x8;
typedef __attribute__((ext_vector_type(4))) float f32x4;

#define N_ROWS 16384
#define M_COLS 16384
#define DIM    64
#define SLICES 16
#define JTILE  64
#define JSLICE (M_COLS / SLICES)   /* 1024 */
#define NTILES (JSLICE / JTILE)    /* 16   */
#define IBLOCK 128                 /* 4 waves x 32 rows */
#define LOG2E  1.44269504088896340736f

/* ---- workspace layout (bytes) ----
   x0b  bf16[N][64]    @ 0            (2 MB)
   x1b  bf16[M][64]    @ 2 MB         (2 MB)
   s0h  f32[N] (-s0/2) @ 4 MB         (64 KB)
   z    f32x2[M] (c4*s1, y) @ +64 KB  (128 KB)
   num  f32[SLICES][N] @ ...          (1 MB)
   den  f32[SLICES][N] @ ...          (1 MB)   total ~6.2 MB */
#define OFF_X0B 0ull
#define OFF_X1B (OFF_X0B + (size_t)N_ROWS * DIM * 2)
#define OFF_S0H (OFF_X1B + (size_t)M_COLS * DIM * 2)
#define OFF_Z   (OFF_S0H + (size_t)N_ROWS * 4)
#define OFF_NUM (OFF_Z + (size_t)M_COLS * 8)
#define OFF_DEN (OFF_NUM + (size_t)SLICES * N_ROWS * 4)

// ---------------- precompute: fp32 -> bf16 (RNE) + folded row norms ---------
__global__ __launch_bounds__(256) void prep_kernel(
    const float* __restrict__ x0, const float* __restrict__ x1,
    const float* __restrict__ y, const float* __restrict__ alpha,
    u16* __restrict__ x0b, u16* __restrict__ x1b,
    float* __restrict__ s0h, float2* __restrict__ z) {
  int wave = (blockIdx.x * 256 + threadIdx.x) >> 6;   // one wave per row
  int lane = threadIdx.x & 63;
  float ca = alpha[0] * LOG2E;
  float c4 = ca * ca;                                  // (alpha*log2e)^2
  const float* src; u16* dstb; int row; bool isX0;
  if (wave < N_ROWS) { row = wave;          src = x0; dstb = x0b; isX0 = true;  }
  else               { row = wave - N_ROWS; src = x1; dstb = x1b; isX0 = false; }
  float v = src[(size_t)row * DIM + lane];
  float sq = v * v;
  #pragma unroll
  for (int o = 32; o; o >>= 1) sq += __shfl_xor(sq, o);
  if (lane == 0) {
    if (isX0) s0h[row] = -0.5f * sq;                  // acc-init value
    else      z[row] = make_float2(c4 * sq, y[row]);  // folded s1 + y
  }
  uint32_t u = __float_as_uint(v);
  u += 0x7FFFu + ((u >> 16) & 1u);                    // RNE to bf16
  dstb[(size_t)row * DIM + lane] = (u16)(u >> 16);
}

// ---------------- main: flash-style dist+softmax, bf16 MFMA ------------------
// Block = 256 thr (4 waves). Wave w owns 32 i-rows (2 x 16-tiles), A-frags +
// s0-halves in registers. j in 64-wide LDS tiles, double-buffered,
// 1 barrier/tile (prefetch issued right AFTER the barrier so the vmcnt(0)
// drain at the next barrier lands a full tile-compute later).
#define STAGE(bufi, jb)                                                        \
  do {                                                                         \
    _Pragma("unroll")                                                          \
    for (int rd = 0; rd < 2; ++rd) {                                           \
      int ci = rd * 256 + tid;         /* 16B-chunk, 0..511 */                 \
      int rr = ci >> 3, ss = ci & 7;                                           \
      const u16* srcp = x1b + (size_t)(jb + rr) * DIM + ((ss ^ (rr & 7)) << 3);\
      __builtin_amdgcn_global_load_lds(                                        \
          (const __attribute__((address_space(1))) unsigned int*)srcp,         \
          (__attribute__((address_space(3))) unsigned int*)(&ldsB[bufi][0] + ci * 8), \
          16, 0, 0);                                                           \
    }                                                                          \
  } while (0)

__global__ __launch_bounds__(256, 4) void dist_softmax_kernel(
    const u16* __restrict__ x0b, const u16* __restrict__ x1b,
    const float* __restrict__ s0h, const float2* __restrict__ z,
    const float* __restrict__ alpha,
    float* __restrict__ numOut, float* __restrict__ denOut) {
  __shared__ u16 ldsB[2][JTILE * DIM];            // 2 x 8 KB, XOR-swizzled

  const int tid  = threadIdx.x;
  const int lane = tid & 63;
  const int w    = tid >> 6;
  const int r16  = lane & 15;
  const int g    = lane >> 4;
  const int iBase = blockIdx.x * IBLOCK + w * 32;
  const int jSliceBase = blockIdx.y * JSLICE;
  float ca = alpha[0] * LOG2E;
  const float m2c4 = -2.0f * ca * ca;             // -2*(alpha*log2e)^2

  // A fragments: lane layout A[l&15][(l>>4)*8 + e]
  bf16x8 a[2][2];
  #pragma unroll
  for (int m2 = 0; m2 < 2; ++m2)
    #pragma unroll
    for (int kk = 0; kk < 2; ++kk)
      a[m2][kk] = *reinterpret_cast<const bf16x8*>(
          x0b + (size_t)(iBase + m2 * 16 + r16) * DIM + kk * 32 + g * 8);

  // -s0/2 per C/D slot: row = m2*16 + g*4 + r
  float s0r[2][4];
  #pragma unroll
  for (int m2 = 0; m2 < 2; ++m2)
    #pragma unroll
    for (int r = 0; r < 4; ++r)
      s0r[m2][r] = s0h[iBase + m2 * 16 + g * 4 + r];

  float num[2][4], den[2][4];
  #pragma unroll
  for (int m2 = 0; m2 < 2; ++m2)
    #pragma unroll
    for (int r = 0; r < 4; ++r) { num[m2][r] = 0.f; den[m2][r] = 0.f; }

  STAGE(0, jSliceBase);                           // prologue: tile 0

  for (int jt = 0; jt < NTILES; ++jt) {
    __syncthreads();                              // tile jt staged; old readers done
    if (jt + 1 < NTILES) STAGE((jt + 1) & 1, jSliceBase + (jt + 1) * JTILE);
    const u16* buf = &ldsB[jt & 1][0];
    const int jBase = jSliceBase + jt * JTILE;

    #pragma unroll 2
    for (int nt = 0; nt < 4; ++nt) {
      const int n = nt * 16 + r16;
      bf16x8 b0 = *reinterpret_cast<const bf16x8*>(buf + n * DIM + ((g ^ (n & 7)) << 3));
      bf16x8 b1 = *reinterpret_cast<const bf16x8*>(buf + n * DIM + (((4 + g) ^ (n & 7)) << 3));

      f32x4 acc[2];
      #pragma unroll
      for (int m2 = 0; m2 < 2; ++m2)
        acc[m2] = (f32x4){s0r[m2][0], s0r[m2][1], s0r[m2][2], s0r[m2][3]};
      #pragma unroll
      for (int m2 = 0; m2 < 2; ++m2) {
        acc[m2] = __builtin_amdgcn_mfma_f32_16x16x32_bf16(a[m2][0], b0, acc[m2], 0, 0, 0);
        acc[m2] = __builtin_amdgcn_mfma_f32_16x16x32_bf16(a[m2][1], b1, acc[m2], 0, 0, 0);
      }
      // acc = dot - s0/2;  q = c4*(s0+s1-2dot) = fma(-2c4, acc, c4*s1)
      float2 zc = z[jBase + nt * 16 + r16];
      #pragma unroll
      for (int m2 = 0; m2 < 2; ++m2)
        #pragma unroll
        for (int r = 0; r < 4; ++r) {
          float q = fmaf(m2c4, acc[m2][r], zc.x);
          q = fmaxf(q, 0.f);
          float t = __builtin_amdgcn_sqrtf(q);
          float e = __builtin_amdgcn_exp2f(-t);   // 2^(-a*log2e*dist)
          den[m2][r] += e;
          num[m2][r] = fmaf(e, zc.y, num[m2][r]);
        }
    }
  }

  // reduce across the 16 lanes sharing each output row
  #pragma unroll
  for (int m2 = 0; m2 < 2; ++m2)
    #pragma unroll
    for (int r = 0; r < 4; ++r) {
      float nv = num[m2][r], dv = den[m2][r];
      #pragma unroll
      for (int o = 1; o < 16; o <<= 1) {
        nv += __shfl_xor(nv, o);
        dv += __shfl_xor(dv, o);
      }
      if (r16 == 0) {
        int row = iBase + m2 * 16 + g * 4 + r;
        numOut[(size_t)blockIdx.y * N_ROWS + row] = nv;
        denOut[(size_t)blockIdx.y * N_ROWS + row] = dv;
      }
    }
}

// ---------------- combine slices ---------------------------------------------
__global__ __launch_bounds__(256) void combine_kernel(
    const float* __restrict__ num, const float* __restrict__ den,
    float* __restrict__ out) {
  int i = blockIdx.x * 256 + threadIdx.x;
  float nv = 0.f, dv = 0.f;
  #pragma unroll
  for (int s = 0; s < SLICES; ++s) {
    nv += num[(size_t)s * N_ROWS + i];
    dv += den[(size_t)s * N_ROWS + i];
  }
  out[i] = nv / dv;
}

extern "C" void kernel_launch(void* const* d_in, const int* in_sizes, int n_in,
                              void* d_out, int out_size, void* d_ws, size_t ws_size,
                              hipStream_t stream) {
  const float* x0    = (const float*)d_in[0];
  const float* x1    = (const float*)d_in[1];
  const float* y     = (const float*)d_in[2];
  const float* alpha = (const float*)d_in[3];
  float* out = (float*)d_out;

  char* ws = (char*)d_ws;
  u16*    x0b = (u16*)(ws + OFF_X0B);
  u16*    x1b = (u16*)(ws + OFF_X1B);
  float*  s0h = (float*)(ws + OFF_S0H);
  float2* zz  = (float2*)(ws + OFF_Z);
  float*  num = (float*)(ws + OFF_NUM);
  float*  den = (float*)(ws + OFF_DEN);

  prep_kernel<<<dim3(2 * N_ROWS / 4), dim3(256), 0, stream>>>(
      x0, x1, y, alpha, x0b, x1b, s0h, zz);

  dist_softmax_kernel<<<dim3(N_ROWS / IBLOCK, SLICES), dim3(256), 0, stream>>>(
      x0b, x1b, s0h, zz, alpha, num, den);

  combine_kernel<<<dim3(N_ROWS / 256), dim3(256), 0, stream>>>(num, den, out);
}